// Round 11
// baseline (185.308 us; speedup 1.0000x reference)
//
#include <hip/hip_runtime.h>
#include <cstdint>
#include <cstddef>

// ---------- types ----------
typedef __bf16 bf16;
typedef bf16  bf16x4  __attribute__((ext_vector_type(4)));
typedef bf16  bf16x8  __attribute__((ext_vector_type(8)));
typedef float floatx4 __attribute__((ext_vector_type(4)));

// Problem constants (reference: B=2, S=2048, D=1024, H=16, Dh=64)
#define BATCH 2
#define SEQ   2048
#define DIM   1024
#define NH    16
#define DH    64
#define D3    3072
#define MROWS 4096   // BATCH*SEQ

// async global->LDS, 16B per lane; LDS dest must be wave-uniform base + lane*16
__device__ __forceinline__ void gld16(void* lds, const void* gptr) {
  __builtin_amdgcn_global_load_lds(
      (const __attribute__((address_space(1))) unsigned int*)gptr,
      (__attribute__((address_space(3))) unsigned int*)lds, 16, 0, 0);
}

// ---------- kernel 1: merged prep ----------
// blocks [0,4096): x fp32 -> bf16        (1M float4)
// blocks [4096,7168): W_in  [1024][3072] -> W_in^T  bf16 (32x32 tiles)
// blocks [7168,8192): W_out [1024][1024] -> W_out^T bf16 (32x32 tiles)
__global__ __launch_bounds__(256) void k_prep(const float4* __restrict__ x,
                                              bf16* __restrict__ xb,
                                              const float* __restrict__ Wi,
                                              bf16* __restrict__ wti,
                                              const float* __restrict__ Wo,
                                              bf16* __restrict__ wto) {
  __shared__ float tile[32][33];
  const int bid = blockIdx.x;
  if (bid < 4096) {
    int i = bid * 256 + threadIdx.x;
    float4 v = x[i];
    bf16x4 o;
    o.x = (bf16)v.x; o.y = (bf16)v.y; o.z = (bf16)v.z; o.w = (bf16)v.w;
    *(bf16x4*)(xb + (size_t)i * 4) = o;
    return;
  }
  const float* W; bf16* Wt; int N, id;
  if (bid < 7168) { W = Wi; Wt = wti; N = 3072; id = bid - 4096; }
  else            { W = Wo; Wt = wto; N = 1024; id = bid - 7168; }
  const int nb = N / 32;
  int n0 = (id % nb) * 32, k0 = (id / nb) * 32;
  int tx = threadIdx.x & 31, ty = threadIdx.x >> 5;   // ty in [0,8)
#pragma unroll
  for (int i = 0; i < 4; i++)
    tile[ty + i * 8][tx] = W[(size_t)(k0 + ty + i * 8) * N + n0 + tx];
  __syncthreads();
#pragma unroll
  for (int i = 0; i < 4; i++)
    Wt[(size_t)(n0 + ty + i * 8) * 1024 + k0 + tx] = (bf16)tile[tx][ty + i * 8];
}

// ---------- kernel 2: GEMM  C = A[M][K] * Bt[N][K]^T  (3-buf pipelined K-loop) ----------
// BMxBN tile, BK=32, 4 waves in 2x2 (each (BM/2)x(BN/2)). XOR chunk swizzle.
// Triple-buffered staging, raw s_barrier + manual s_waitcnt vmcnt(LN) (never 0
// mid-loop). 2D grid, x = N-major (consecutive blocks share A-tile in L2).
// MODE 0: plain C[M][N]. MODE 1: qkv-split epilogue (qk stride 2048 / vt transposed).
template <typename OutT, int MODE, int BM, int BN>
__global__ __launch_bounds__(256) void k_gemm_bt(const bf16* __restrict__ A,
                                                 const bf16* __restrict__ Bt,
                                                 OutT* __restrict__ C,
                                                 bf16* __restrict__ qk,
                                                 bf16* __restrict__ vt,
                                                 int M, int N, int K) {
  constexpr int LN = BM / 64 + BN / 64;            // gld16 per thread per stage
  constexpr int MT = BM / 32, NT = BN / 32;        // subtiles per wave (2x2 wave grid)
  __shared__ __align__(16) bf16 As[3][BM * 32];
  __shared__ __align__(16) bf16 Bs[3][BN * 32];
  const int t = threadIdx.x, l = t & 63, w = t >> 6;
  const int q = l >> 4, mm = l & 15;
  const int m0 = blockIdx.y * BM, n0 = blockIdx.x * BN;
  const int mo = (w >> 1) * (BM / 2);
  const int no = (w & 1) * (BN / 2);
  const int sw = (mm >> 1) & 3;                    // fragment-read swizzle

  auto stage = [&](int kt) {
    const int bp = kt % 3;
#pragma unroll
    for (int i = 0; i < BM / 64; i++) {            // BM*4 A-chunks of 16B
      int c = t + i * 256;
      int row = c >> 2, pos = c & 3;
      int gs = pos ^ ((row >> 1) & 3);
      gld16((char*)As[bp] + (size_t)c * 16, A + (size_t)(m0 + row) * K + kt * 32 + gs * 8);
    }
#pragma unroll
    for (int i = 0; i < BN / 64; i++) {            // BN*4 B-chunks
      int c = t + i * 256;
      int row = c >> 2, pos = c & 3;
      int gs = pos ^ ((row >> 1) & 3);
      gld16((char*)Bs[bp] + (size_t)c * 16, Bt + (size_t)(n0 + row) * K + kt * 32 + gs * 8);
    }
  };

  floatx4 acc[MT][NT] = {};
  const int nk = K >> 5;

  stage(0);
  stage(1);                                // 2*LN loads outstanding

  for (int kt = 0; kt < nk; kt++) {
    // stage(kt) landed (mine); join all waves. Never vmcnt(0) until the tail.
    if (kt + 1 < nk)
      asm volatile("s_waitcnt vmcnt(%0)\n\ts_barrier" :: "n"(LN) : "memory");
    else
      asm volatile("s_waitcnt vmcnt(0)\n\ts_barrier" ::: "memory");
    if (kt + 2 < nk) stage(kt + 2);        // overwrites buf[(kt-1)%3]; safe post-barrier

    const bf16* Ab = As[kt % 3];
    const bf16* Bb = Bs[kt % 3];
    bf16x8 af[MT], bfr[NT];
#pragma unroll
    for (int mt = 0; mt < MT; mt++)
      af[mt] = *(const bf16x8*)(Ab + (size_t)(mo + mt * 16 + mm) * 32 + (q ^ sw) * 8);
#pragma unroll
    for (int nt = 0; nt < NT; nt++)
      bfr[nt] = *(const bf16x8*)(Bb + (size_t)(no + nt * 16 + mm) * 32 + (q ^ sw) * 8);
#pragma unroll
    for (int mt = 0; mt < MT; mt++)
#pragma unroll
      for (int nt = 0; nt < NT; nt++)
        acc[mt][nt] = __builtin_amdgcn_mfma_f32_16x16x32_bf16(af[mt], bfr[nt],
                                                              acc[mt][nt], 0, 0, 0);
  }
  // epilogue: C/D layout col=lane&15, row=(lane>>4)*4+reg (plain stores — R9: NT stores = 3x write amp)
#pragma unroll
  for (int mt = 0; mt < MT; mt++)
#pragma unroll
    for (int nt = 0; nt < NT; nt++)
#pragma unroll
      for (int r = 0; r < 4; r++) {
        int row = m0 + mo + mt * 16 + q * 4 + r;
        int col = n0 + no + nt * 16 + mm;
        if (MODE == 0) {
          C[(size_t)row * N + col] = (OutT)acc[mt][nt][r];
        } else {
          if (col < 2048) {
            qk[(size_t)row * 2048 + col] = (bf16)acc[mt][nt][r];
          } else {
            int d = col - 2048;                  // 0..1023
            int hh = d >> 6, dh = d & 63;
            int bb = row >> 11, s = row & 2047;
            vt[((size_t)(bb * 16 + hh) * 64 + dh) * SEQ + s] = (bf16)acc[mt][nt][r];
          }
        }
      }
}

// ---------- kernel 3: causal flash attention — wave-independent k-strips ----------
// 1024 blocks = (b,h) x 32 q-tiles (qt descending = LPT). Fixed-max softmax has no
// cross-tile coupling, so wave w independently processes k-tiles kt ≡ w (mod 4)
// for ALL 64 q rows (qf[4 groups] in regs) with NO in-loop barriers. K/V fragments
// are loaded directly global->VGPR (each kf feeds 4 q-groups; vf issued at iter
// top, consumed post-softmax = free latency window). Partial O (fp32) and l are
// combined once at the end via LDS (2 barriers total).
__global__ __launch_bounds__(256, 2) void k_attn(const bf16* __restrict__ qk,
                                                 const bf16* __restrict__ vt,
                                                 bf16* __restrict__ out) {
  const int bx = blockIdx.x;
  const int qt = 31 - (bx >> 5);          // descending: LPT order
  const int bh = bx & 31;
  const int b = bh >> 4, h = bh & 15;
  const int t = threadIdx.x, l = t & 63, w = t >> 6;
  const int q4 = l >> 4, mm = l & 15;

  // LDS: Ps[4][16][40] bf16 (5120) + union{ Qs[2][64][32] bf16 (8192) ;
  //       Opart[4][64][65] fp32 (66560) + Lpart[4][64] fp32 (1024) } = 72704 B
  __shared__ __align__(16) char lds[5120 + 66560 + 1024];
  bf16*  Ps    = (bf16*)lds;              // per-wave +w*640 elems, row stride 40
  bf16*  Qs    = (bf16*)(lds + 5120);
  float* Opart = (float*)(lds + 5120);            // [w][d=64][q=64] stride 65
  float* Lpart = (float*)(lds + 5120 + 66560);    // [w][q=64]

  const size_t qkbase = (size_t)b * SEQ * 2048;
  const bf16* kb = qk + qkbase + 1024 + h * 64;   // K base, row stride 2048
  const bf16* vb = vt + (size_t)bh * 64 * SEQ;    // V^T base, row stride 2048

  { // stage Q tile once: 64 rows x 64 cols -> [ks][64][32]
    int row = t >> 2, col = (t & 3) * 8;
#pragma unroll
    for (int i = 0; i < 2; i++)
      gld16((char*)Qs + ((size_t)t + i * 256) * 16,
            qk + qkbase + (size_t)(qt * 64 + row) * 2048 + h * 64 + i * 32 + col);
  }
  __syncthreads();                        // Q landed
  bf16x8 qf[4][2];                        // all 4 q-groups per wave
#pragma unroll
  for (int g = 0; g < 4; g++)
#pragma unroll
    for (int ks = 0; ks < 2; ks++) {
      qf[g][ks] = *(const bf16x8*)(Qs + (size_t)(ks * 64 + g * 16 + mm) * 32 + q4 * 8);
#pragma unroll
      for (int j = 0; j < 8; j++)         // 1/sqrt(64) * log2(e): exp2-domain softmax
        qf[g][ks][j] = (bf16)((float)qf[g][ks][j] * 0.18033688f);
    }
  __syncthreads();                        // all waves done with Qs (Opart overlays it)

  float l_i[4] = {0.f, 0.f, 0.f, 0.f};
  floatx4 oacc[4][4] = {};                // [g][nt]: O^T rows d=nt*16+q4*4+r, col q=g*16+mm
  const float FM = 24.0f;                 // fixed log2-domain max bound
  bf16* Pw = Ps + (size_t)w * 640;        // this wave's P region [16][40]

  for (int kt = w; kt <= qt; kt += 4) {   // wave-private k-strip, no barriers
    bf16x8 kf[2][4], vf[2][4];
#pragma unroll
    for (int ks = 0; ks < 2; ks++)
#pragma unroll
      for (int ct = 0; ct < 4; ct++)
        kf[ks][ct] = *(const bf16x8*)(kb + (size_t)(kt * 64 + ct * 16 + mm) * 2048 +
                                      ks * 32 + q4 * 8);
#pragma unroll
    for (int ks = 0; ks < 2; ks++)
#pragma unroll
      for (int nt = 0; nt < 4; nt++)
        vf[ks][nt] = *(const bf16x8*)(vb + (size_t)(nt * 16 + mm) * 2048 +
                                      kt * 64 + ks * 32 + q4 * 8);
    const bool diag = (kt == qt);

#pragma unroll
    for (int g = 0; g < 4; g++) {
      floatx4 sacc[4] = {};
#pragma unroll
      for (int ks = 0; ks < 2; ks++)
#pragma unroll
        for (int ct = 0; ct < 4; ct++)
          sacc[ct] = __builtin_amdgcn_mfma_f32_16x16x32_bf16(kf[ks][ct], qf[g][ks],
                                                             sacc[ct], 0, 0, 0);
      // fixed-max softmax (log2 units)
      bf16x4 pk[4];
      float rsum = 0.f;
      const int qloc = g * 16 + mm;
      if (diag) {
#pragma unroll
        for (int ct = 0; ct < 4; ct++)
#pragma unroll
          for (int r = 0; r < 4; r++) {
            float e = (ct * 16 + q4 * 4 + r > qloc)
                          ? 0.f : __builtin_amdgcn_exp2f(sacc[ct][r] - FM);
            pk[ct][r] = (bf16)e;
            rsum += e;
          }
      } else {
#pragma unroll
        for (int ct = 0; ct < 4; ct++)
#pragma unroll
          for (int r = 0; r < 4; r++) {
            float e = __builtin_amdgcn_exp2f(sacc[ct][r] - FM);
            pk[ct][r] = (bf16)e;
            rsum += e;
          }
      }
      rsum += __shfl_xor(rsum, 16, 64);
      rsum += __shfl_xor(rsum, 32, 64);
      l_i[g] += rsum;

      // P^T -> B-operand layout via per-wave LDS (in-wave DS ordering, no barrier)
#pragma unroll
      for (int ks = 0; ks < 2; ks++) {
        *(bf16x4*)(Pw + (size_t)mm * 40 + q4 * 4)      = pk[ks * 2 + 0];
        *(bf16x4*)(Pw + (size_t)mm * 40 + 16 + q4 * 4) = pk[ks * 2 + 1];
        bf16x8 pf = *(const bf16x8*)(Pw + (size_t)mm * 40 + q4 * 8);
#pragma unroll
        for (int nt = 0; nt < 4; nt++)
          oacc[g][nt] = __builtin_amdgcn_mfma_f32_16x16x32_bf16(vf[ks][nt], pf,
                                                                oacc[g][nt], 0, 0, 0);
      }
    }
  }

  // write partials (idle waves write zeros — uniform path)
#pragma unroll
  for (int g = 0; g < 4; g++) {
#pragma unroll
    for (int nt = 0; nt < 4; nt++)
#pragma unroll
      for (int r = 0; r < 4; r++)
        Opart[(size_t)w * 4160 + (nt * 16 + q4 * 4 + r) * 65 + g * 16 + mm] = oacc[g][nt][r];
    if (q4 == 0) Lpart[w * 64 + g * 16 + mm] = l_i[g];
  }
  __syncthreads();

  // cross-wave reduction: thread t -> d = t&63, q-block = (t>>6)*16
  {
    const int d = t & 63, qb = (t >> 6) * 16;
#pragma unroll
    for (int i = 0; i < 16; i++) {
      int qq = qb + i;
      float lsum = Lpart[qq] + Lpart[64 + qq] + Lpart[128 + qq] + Lpart[192 + qq];
      float v = Opart[(size_t)d * 65 + qq] + Opart[4160 + (size_t)d * 65 + qq] +
                Opart[8320 + (size_t)d * 65 + qq] + Opart[12480 + (size_t)d * 65 + qq];
      out[((size_t)b * SEQ + qt * 64 + qq) * DIM + h * 64 + d] = (bf16)(v / lsum);
    }
  }
}

// ---------- launch ----------
extern "C" void kernel_launch(void* const* d_in, const int* in_sizes, int n_in,
                              void* d_out, int out_size, void* d_ws, size_t ws_size,
                              hipStream_t stream) {
  const float* x     = (const float*)d_in[0];   // [2,2048,1024]
  const float* W_in  = (const float*)d_in[1];   // [1024,3072]
  const float* W_out = (const float*)d_in[2];   // [1024,1024]
  float* out = (float*)d_out;                   // [2,2048,1024]

  char* ws = (char*)d_ws;
  bf16* xb   = (bf16*)(ws);                       //  8 MB: x bf16 [4096][1024] (reused: attn out)
  bf16* wti  = (bf16*)(ws + 8388608);             //  6 MB: W_in^T  [3072][1024]
  bf16* wto  = (bf16*)(ws + 14680064);            //  2 MB: W_out^T [1024][1024]
  bf16* qkb  = (bf16*)(ws + 16777216);            // 16 MB: QK bf16 [4096][2048]
  bf16* vtb  = (bf16*)(ws + 33554432);            //  8 MB: V^T bf16 [32*64][2048]
  bf16* attn = xb;                                //  reuse: xb dead after GEMM1

  k_prep<<<8192, 256, 0, stream>>>((const float4*)x, xb, W_in, wti, W_out, wto);
  // GEMM1: M=4096 N=3072 K=1024; 128x128, 2D grid, x-major shares A-tiles in L2.
  k_gemm_bt<bf16, 1, 128, 128><<<dim3(24, 32), 256, 0, stream>>>(xb, wti, nullptr, qkb, vtb,
                                                                 MROWS, D3, DIM);
  k_attn<<<1024, 256, 0, stream>>>(qkb, vtb, attn);
  // GEMM2: M=4096 N=1024 K=1024; 64x64 tiles -> 1024 blocks (4/CU).
  k_gemm_bt<float, 0, 64, 64><<<dim3(16, 64), 256, 0, stream>>>(attn, wto, out, nullptr, nullptr,
                                                                MROWS, DIM, DIM);
}